// Round 10
// baseline (542.846 us; speedup 1.0000x reference)
//
#include <hip/hip_runtime.h>
#include <hip/hip_bf16.h>

#define NNODES 50000
#define NEDGES 800000
#define ETOT   (NNODES + NEDGES)
#define MTILES 3136            // row-tiles of 16: covers 50176 rows
#define MPAD   (MTILES * 16)   // 50176
#define NBLK   196             // ceil(NNODES/256) for the scan

typedef __attribute__((ext_vector_type(8))) short short8;
typedef __attribute__((ext_vector_type(4))) float floatx4;
typedef __attribute__((ext_vector_type(2))) unsigned int uint2v;
typedef __attribute__((ext_vector_type(4))) short short4v;

__device__ __forceinline__ float bf2f(__hip_bfloat16 x) { return __bfloat162float(x); }
__device__ __forceinline__ __hip_bfloat16 f2bf(float f) { return __float2bfloat16(f); }
__device__ __forceinline__ float sane(float v, float c) {
  v = (v == v) ? v : 0.f;
  return fminf(fmaxf(v, -c), c);
}
__device__ __forceinline__ unsigned short bfbits(float f) {
  union { __hip_bfloat16 b; unsigned short u; } cv;
  cv.b = f2bf(f);
  return cv.u;
}

// ---------------- utility ----------------
__global__ void zero_int_kernel(int* __restrict__ p, int n) {
  int i = blockIdx.x * blockDim.x + threadIdx.x;
  if (i < n) p[i] = 0;
}
__global__ void fill_out_kernel(float* __restrict__ o, int n, float v) {
  int i = blockIdx.x * blockDim.x + threadIdx.x;
  if (i < n) o[i] = v;
}
// split x into hi/lo bf16 over [0, NNODES*128); zero-fill [NNODES*128, MPAD*256)
__global__ void split_input_kernel(const float* __restrict__ in,
                                   __hip_bfloat16* __restrict__ hi,
                                   __hip_bfloat16* __restrict__ lo) {
  int i = blockIdx.x * blockDim.x + threadIdx.x;
  if (i >= MPAD * 256) return;
  float v = (i < NNODES * 128) ? sane(in[i], 1e4f) : 0.f;
  __hip_bfloat16 h = f2bf(v);
  hi[i] = h;
  lo[i] = f2bf(v - bf2f(h));
}
// pad 47-vec attention params to 64 with zeros
__global__ void pad47_kernel(const float* __restrict__ a, const float* __restrict__ b,
                             float* __restrict__ ap, float* __restrict__ bp) {
  int i = threadIdx.x;  // 64
  ap[i] = (i < 47) ? sane(a[i], 1e4f) : 0.f;
  bp[i] = (i < 47) ? sane(b[i], 1e4f) : 0.f;
}

// ---------------- CSR build (dst-sorted, DETERMINISTIC) ----------------
__global__ void degree_kernel(const int* __restrict__ ei, int* __restrict__ deg) {
  int p = blockIdx.x * blockDim.x + threadIdx.x;
  if (p >= ETOT) return;
  int dst = (p < NEDGES) ? ei[NEDGES + p] : (p - NEDGES);
  dst = min(max(dst, 0), NNODES - 1);
  atomicAdd(&deg[dst], 1);
}

// --- parallel 3-phase scan ---
__global__ __launch_bounds__(256) void block_sum_kernel(const int* __restrict__ deg,
                                                        int* __restrict__ bsum) {
  __shared__ int sh[256];
  int b = blockIdx.x, t = threadIdx.x;
  int i = b * 256 + t;
  sh[t] = (i < NNODES) ? deg[i] : 0;
  __syncthreads();
  for (int off = 128; off > 0; off >>= 1) {
    if (t < off) sh[t] += sh[t + off];
    __syncthreads();
  }
  if (t == 0) bsum[b] = sh[0];
}

__global__ __launch_bounds__(256) void scan_bsum_kernel(const int* __restrict__ bsum,
                                                        int* __restrict__ boff,
                                                        int* __restrict__ row_ptr) {
  __shared__ int sh[256];
  int t = threadIdx.x;
  int v = (t < NBLK) ? bsum[t] : 0;
  sh[t] = v;
  __syncthreads();
  for (int off = 1; off < 256; off <<= 1) {
    int u = (t >= off) ? sh[t - off] : 0;
    __syncthreads();
    sh[t] += u;
    __syncthreads();
  }
  if (t < NBLK) boff[t] = sh[t] - v;  // exclusive block offset
  if (t == 255) row_ptr[NNODES] = sh[255];
}

__global__ __launch_bounds__(256) void emit_rowptr_kernel(const int* __restrict__ deg,
                                                          const int* __restrict__ boff,
                                                          int* __restrict__ row_ptr,
                                                          int* __restrict__ cursor) {
  __shared__ int sh[256];
  int b = blockIdx.x, t = threadIdx.x;
  int i = b * 256 + t;
  int d = (i < NNODES) ? deg[i] : 0;
  sh[t] = d;
  __syncthreads();
  for (int off = 1; off < 256; off <<= 1) {
    int u = (t >= off) ? sh[t - off] : 0;
    __syncthreads();
    sh[t] += u;
    __syncthreads();
  }
  if (i < NNODES) {
    int v = boff[b] + sh[t] - d;  // exclusive prefix
    row_ptr[i] = v;
    cursor[i] = v;
  }
}

// scatter into TEMP arrays (atomic positions; order repaired by bucket sort)
__global__ void scatter_kernel(const int* __restrict__ ei, int* __restrict__ cursor,
                               int* __restrict__ tmp_src, int* __restrict__ tmp_p) {
  int p = blockIdx.x * blockDim.x + threadIdx.x;
  if (p >= ETOT) return;
  int src, dst;
  if (p < NEDGES) { src = ei[p]; dst = ei[NEDGES + p]; }
  else            { src = p - NEDGES; dst = src; }
  src = min(max(src, 0), NNODES - 1);
  dst = min(max(dst, 0), NNODES - 1);
  int pos = atomicAdd(&cursor[dst], 1);
  pos = min(max(pos, 0), ETOT - 1);
  tmp_src[pos] = src;
  tmp_p[pos] = p;
}

// canonicalize each dst bucket by original edge index p (all p distinct ->
// rank is an exact permutation). One wave per dst; lanes stride elements;
// inner loop over the (L1-resident) bucket. Makes csr_src deterministic
// regardless of atomic resolution order.
__global__ __launch_bounds__(256) void bucket_sort_kernel(const int* __restrict__ row_ptr,
                                                          const int* __restrict__ tmp_src,
                                                          const int* __restrict__ tmp_p,
                                                          int* __restrict__ csr_src) {
  int wid = threadIdx.x >> 6, lane = threadIdx.x & 63;
  int dst = blockIdx.x * 4 + wid;
  if (dst >= NNODES) return;
  int start = row_ptr[dst], end = row_ptr[dst + 1];
  int cnt = end - start;
  for (int i = lane; i < cnt; i += 64) {
    int pi = tmp_p[start + i];
    int si = tmp_src[start + i];
    int rank = 0;
    for (int j = 0; j < cnt; ++j) rank += (tmp_p[start + j] < pi) ? 1 : 0;
    csr_src[start + rank] = si;
  }
}

// ---------------- weight pack (W [K][Nreal] f32 -> fragment-packed W^T) -------
__global__ void pack_w_kernel(const float* __restrict__ W,
                              __hip_bfloat16* __restrict__ Bh,
                              __hip_bfloat16* __restrict__ Bl,
                              int K, int Nreal, int Npad) {
  int idx = blockIdx.x * blockDim.x + threadIdx.x;
  if (idx >= Npad * K) return;
  int e = idx;
  int j = e & 7;    e >>= 3;
  int m = e & 15;   e >>= 4;
  int quad = e & 3; e >>= 2;
  int kch = K >> 5;
  int kk32 = e % kch;
  int nt = e / kch;
  int n = nt * 16 + m;
  int k = kk32 * 32 + quad * 8 + j;
  float v = (n < Nreal) ? sane(W[k * Nreal + n], 1e4f) : 0.f;
  __hip_bfloat16 h = f2bf(v);
  Bh[idx] = h;
  Bl[idx] = f2bf(v - bf2f(h));
}

// ---------------- GEMM + fused attention logits (verified bit-exact) --------
template<int KDIM, int NOUT, int HEADS, int WAVES_N>
__global__ __launch_bounds__(256) void gemm_attn_kernel(
    const __hip_bfloat16* __restrict__ Ah, const __hip_bfloat16* __restrict__ Al,
    const __hip_bfloat16* __restrict__ Bh, const __hip_bfloat16* __restrict__ Bl,
    const float* __restrict__ asv, const float* __restrict__ adv,
    __hip_bfloat16* __restrict__ Ch, float* __restrict__ als, float* __restrict__ ald) {
  constexpr int KCH = KDIM / 32;
  constexpr int CT = (NOUT / 16) / WAVES_N;  // 4
  constexpr int RT = 4;
  constexpr int RGROUPS = 4 / WAVES_N;       // row groups per block
  __shared__ __hip_bfloat16 sAh[2 * 64 * 32];
  __shared__ __hip_bfloat16 sAl[2 * 64 * 32];
  int wave = threadIdx.x >> 6, lane = threadIdx.x & 63;
  int wrow = wave / WAVES_N, wcol = wave % WAVES_N;
  int rt0 = (blockIdx.x * RGROUPS + wrow) * RT;
  int ct0 = wcol * CT;
  int m = lane & 15, quad = lane >> 4;

  const short8* Bph = reinterpret_cast<const short8*>(Bh);
  const short8* Bpl = reinterpret_cast<const short8*>(Bl);

  floatx4 acc[RT][CT];
#pragma unroll
  for (int rt = 0; rt < RT; ++rt)
#pragma unroll
    for (int ct = 0; ct < CT; ++ct) acc[rt][ct] = (floatx4){0.f, 0.f, 0.f, 0.f};

  int tid = threadIdx.x;
  size_t gstage = (size_t)(rt0 * 16 + (tid >> 2)) * KDIM + (tid & 3) * 8;

#pragma unroll 2
  for (int ks = 0; ks < KCH / 2; ++ks) {
    short8 a_h[RT], a_l[RT];
    if constexpr (WAVES_N == 4) {
      // stage slices 2ks and 2ks+1 together
      short8 vh0 = *reinterpret_cast<const short8*>(Ah + gstage + ks * 64);
      short8 vh1 = *reinterpret_cast<const short8*>(Ah + gstage + ks * 64 + 32);
      short8 vl0 = *reinterpret_cast<const short8*>(Al + gstage + ks * 64);
      short8 vl1 = *reinterpret_cast<const short8*>(Al + gstage + ks * 64 + 32);
      __syncthreads();  // prior stage's reads complete before overwrite
      *reinterpret_cast<short8*>(&sAh[tid * 8]) = vh0;
      *reinterpret_cast<short8*>(&sAh[2048 + tid * 8]) = vh1;
      *reinterpret_cast<short8*>(&sAl[tid * 8]) = vl0;
      *reinterpret_cast<short8*>(&sAl[2048 + tid * 8]) = vl1;
      __syncthreads();
#pragma unroll
      for (int kk0 = 0; kk0 < 2; ++kk0) {
#pragma unroll
        for (int rt = 0; rt < RT; ++rt) {
          int so = kk0 * 2048 + (rt * 16 + m) * 32 + quad * 8;
          a_h[rt] = *reinterpret_cast<const short8*>(&sAh[so]);
          a_l[rt] = *reinterpret_cast<const short8*>(&sAl[so]);
        }
        int kk = ks * 2 + kk0;
#pragma unroll
        for (int ct = 0; ct < CT; ++ct) {
          size_t o = ((size_t)(ct0 + ct) * KCH + kk) * 64 + lane;
          short8 b_h = Bph[o];
          short8 b_l = Bpl[o];
#pragma unroll
          for (int rt = 0; rt < RT; ++rt) {
            acc[rt][ct] = __builtin_amdgcn_mfma_f32_16x16x32_bf16(a_h[rt], b_h, acc[rt][ct], 0, 0, 0);
            acc[rt][ct] = __builtin_amdgcn_mfma_f32_16x16x32_bf16(a_h[rt], b_l, acc[rt][ct], 0, 0, 0);
            acc[rt][ct] = __builtin_amdgcn_mfma_f32_16x16x32_bf16(a_l[rt], b_h, acc[rt][ct], 0, 0, 0);
          }
        }
      }
    } else {
#pragma unroll
      for (int kk0 = 0; kk0 < 2; ++kk0) {
        int kk = ks * 2 + kk0;
#pragma unroll
        for (int rt = 0; rt < RT; ++rt) {
          size_t aoff = (size_t)((rt0 + rt) * 16 + m) * KDIM + kk * 32 + quad * 8;
          a_h[rt] = *reinterpret_cast<const short8*>(Ah + aoff);
          a_l[rt] = *reinterpret_cast<const short8*>(Al + aoff);
        }
#pragma unroll
        for (int ct = 0; ct < CT; ++ct) {
          size_t o = ((size_t)(ct0 + ct) * KCH + kk) * 64 + lane;
          short8 b_h = Bph[o];
          short8 b_l = Bpl[o];
#pragma unroll
          for (int rt = 0; rt < RT; ++rt) {
            acc[rt][ct] = __builtin_amdgcn_mfma_f32_16x16x32_bf16(a_h[rt], b_h, acc[rt][ct], 0, 0, 0);
            acc[rt][ct] = __builtin_amdgcn_mfma_f32_16x16x32_bf16(a_h[rt], b_l, acc[rt][ct], 0, 0, 0);
            acc[rt][ct] = __builtin_amdgcn_mfma_f32_16x16x32_bf16(a_l[rt], b_h, acc[rt][ct], 0, 0, 0);
          }
        }
      }
    }
  }

  // fused attention logits: this wave's CT*16 cols lie in exactly one head
  constexpr int CPH = NOUT / HEADS;
  int head = (ct0 * 16) / CPH;
  float asl[CT], adl[CT];
#pragma unroll
  for (int ct = 0; ct < CT; ++ct) {
    asl[ct] = asv[(ct0 + ct) * 16 + m];
    adl[ct] = adv[(ct0 + ct) * 16 + m];
  }
  float ps[RT * 4], pd[RT * 4];
#pragma unroll
  for (int i = 0; i < RT * 4; ++i) { ps[i] = 0.f; pd[i] = 0.f; }
#pragma unroll
  for (int rt = 0; rt < RT; ++rt)
#pragma unroll
    for (int ct = 0; ct < CT; ++ct)
#pragma unroll
      for (int r = 0; r < 4; ++r) {
        ps[rt * 4 + r] += acc[rt][ct][r] * asl[ct];
        pd[rt * 4 + r] += acc[rt][ct][r] * adl[ct];
      }
#pragma unroll
  for (int off = 1; off < 16; off <<= 1) {
#pragma unroll
    for (int i = 0; i < RT * 4; ++i) {
      ps[i] += __shfl_xor(ps[i], off);
      pd[i] += __shfl_xor(pd[i], off);
    }
  }
  if (m == 0) {
#pragma unroll
    for (int rt = 0; rt < RT; ++rt)
#pragma unroll
      for (int r = 0; r < 4; ++r) {
        int row = (rt0 + rt) * 16 + quad * 4 + r;
        if (row < NNODES) {
          als[(size_t)row * HEADS + head] = sane(ps[rt * 4 + r], 80.f);
          ald[(size_t)row * HEADS + head] = sane(pd[rt * 4 + r], 80.f);
        }
      }
  }

  // store C (hi-only bf16, row-major for the aggregation gather)
#pragma unroll
  for (int rt = 0; rt < RT; ++rt)
#pragma unroll
    for (int ct = 0; ct < CT; ++ct)
#pragma unroll
      for (int r = 0; r < 4; ++r) {
        int row = (rt0 + rt) * 16 + quad * 4 + r;
        if (row < NNODES) {
          float v = sane(acc[rt][ct][r], 3e4f);
          Ch[(size_t)row * NOUT + (ct0 + ct) * 16 + m] = f2bf(v);
        }
      }
}

// ---------------- normalized edge weights (alpha) ----------------
template<int H>
__global__ __launch_bounds__(256) void alpha_kernel(const int* __restrict__ row_ptr,
                                                    const int* __restrict__ csr_src,
                                                    const float* __restrict__ als,
                                                    const float* __restrict__ ald,
                                                    float* __restrict__ alpha) {
  int wid = threadIdx.x >> 6, lane = threadIdx.x & 63;
  int dst = blockIdx.x * 4 + wid;
  if (dst >= NNODES) return;
  int start = row_ptr[dst], end = row_ptr[dst + 1];
  int cnt = end - start;
  if (cnt <= 0) return;
  float adv[H];
#pragma unroll
  for (int h = 0; h < H; ++h) adv[h] = ald[(size_t)dst * H + h];

  if (cnt <= 64) {
    int i = start + lane;
    bool valid = lane < cnt;
    int s = valid ? min(max(csr_src[i], 0), NNODES - 1) : 0;
    float w[H];
#pragma unroll
    for (int h = 0; h < H; ++h) {
      float e = als[(size_t)s * H + h] + adv[h];
      e = e > 0.f ? e : 0.2f * e;
      e = fminf(fmaxf(e, -80.f), 80.f);
      w[h] = valid ? __expf(e) : 0.f;
    }
#pragma unroll
    for (int h = 0; h < H; ++h) {
      float v = w[h];
#pragma unroll
      for (int off = 1; off < 64; off <<= 1) v += __shfl_xor(v, off);
      float inv = 1.f / fmaxf(v, 1e-30f);
      if (valid) alpha[(size_t)i * H + h] = w[h] * inv;
    }
  } else {
    float dl[H];
#pragma unroll
    for (int h = 0; h < H; ++h) dl[h] = 0.f;
    for (int base = start; base < end; base += 64) {
      int i = base + lane;
      bool valid = i < end;
      int s = valid ? min(max(csr_src[i], 0), NNODES - 1) : 0;
#pragma unroll
      for (int h = 0; h < H; ++h) {
        float e = als[(size_t)s * H + h] + adv[h];
        e = e > 0.f ? e : 0.2f * e;
        e = fminf(fmaxf(e, -80.f), 80.f);
        float w = valid ? __expf(e) : 0.f;
        dl[h] += w;
        if (valid) alpha[(size_t)i * H + h] = w;
      }
    }
    float inv[H];
#pragma unroll
    for (int h = 0; h < H; ++h) {
      float v = dl[h];
#pragma unroll
      for (int off = 1; off < 64; off <<= 1) v += __shfl_xor(v, off);
      inv[h] = 1.f / fmaxf(v, 1e-30f);
    }
    for (int base = start; base < end; base += 64) {
      int i = base + lane;
      if (i < end)
#pragma unroll
        for (int h = 0; h < H; ++h) alpha[(size_t)i * H + h] *= inv[h];
    }
  }
}

// ---------------- aggregation, mid layers (T=256, H=4) ----------------
// ONE WAVE PER DST; lane owns 4 cols (uint2 8B load -> 512B/wave-instr);
// EIGHT edges in flight (8 independent load chains), two accumulator chains;
// no LDS, no barriers. Epilogue (bias+ELU+hi/lo split) from registers.
__global__ __launch_bounds__(256) void agg_mid_kernel(const int* __restrict__ row_ptr,
                                                      const int* __restrict__ csr_src,
                                                      const __hip_bfloat16* __restrict__ Fh,
                                                      const float* __restrict__ alpha,
                                                      const float* __restrict__ bias,
                                                      __hip_bfloat16* __restrict__ Oh,
                                                      __hip_bfloat16* __restrict__ Ol) {
  int wid = threadIdx.x >> 6, lane = threadIdx.x & 63;
  int dst = blockIdx.x * 4 + wid;
  if (dst >= NNODES) return;
  int start = row_ptr[dst], end = row_ptr[dst + 1];
  int cnt = end - start;
  int head = lane >> 4;
  float a0 = 0.f, a1 = 0.f, a2 = 0.f, a3 = 0.f;
  float b0 = 0.f, b1 = 0.f, b2 = 0.f, b3 = 0.f;
  int p = 0;
  for (; p + 7 < cnt; p += 8) {  // 8 edges in flight
    int e0 = start + p;
    int s0 = csr_src[e0],     s1 = csr_src[e0 + 1], s2 = csr_src[e0 + 2], s3 = csr_src[e0 + 3];
    int s4 = csr_src[e0 + 4], s5 = csr_src[e0 + 5], s6 = csr_src[e0 + 6], s7 = csr_src[e0 + 7];
    float w0 = alpha[(size_t)(e0    ) * 4 + head];
    float w1 = alpha[(size_t)(e0 + 1) * 4 + head];
    float w2 = alpha[(size_t)(e0 + 2) * 4 + head];
    float w3 = alpha[(size_t)(e0 + 3) * 4 + head];
    float w4 = alpha[(size_t)(e0 + 4) * 4 + head];
    float w5 = alpha[(size_t)(e0 + 5) * 4 + head];
    float w6 = alpha[(size_t)(e0 + 6) * 4 + head];
    float w7 = alpha[(size_t)(e0 + 7) * 4 + head];
    uint2v f0 = *reinterpret_cast<const uint2v*>(Fh + (size_t)s0 * 256 + lane * 4);
    uint2v f1 = *reinterpret_cast<const uint2v*>(Fh + (size_t)s1 * 256 + lane * 4);
    uint2v f2 = *reinterpret_cast<const uint2v*>(Fh + (size_t)s2 * 256 + lane * 4);
    uint2v f3 = *reinterpret_cast<const uint2v*>(Fh + (size_t)s3 * 256 + lane * 4);
    uint2v f4 = *reinterpret_cast<const uint2v*>(Fh + (size_t)s4 * 256 + lane * 4);
    uint2v f5 = *reinterpret_cast<const uint2v*>(Fh + (size_t)s5 * 256 + lane * 4);
    uint2v f6 = *reinterpret_cast<const uint2v*>(Fh + (size_t)s6 * 256 + lane * 4);
    uint2v f7 = *reinterpret_cast<const uint2v*>(Fh + (size_t)s7 * 256 + lane * 4);
    a0 += w0 * __uint_as_float(f0.x << 16);
    a1 += w0 * __uint_as_float(f0.x & 0xffff0000u);
    a2 += w0 * __uint_as_float(f0.y << 16);
    a3 += w0 * __uint_as_float(f0.y & 0xffff0000u);
    b0 += w1 * __uint_as_float(f1.x << 16);
    b1 += w1 * __uint_as_float(f1.x & 0xffff0000u);
    b2 += w1 * __uint_as_float(f1.y << 16);
    b3 += w1 * __uint_as_float(f1.y & 0xffff0000u);
    a0 += w2 * __uint_as_float(f2.x << 16);
    a1 += w2 * __uint_as_float(f2.x & 0xffff0000u);
    a2 += w2 * __uint_as_float(f2.y << 16);
    a3 += w2 * __uint_as_float(f2.y & 0xffff0000u);
    b0 += w3 * __uint_as_float(f3.x << 16);
    b1 += w3 * __uint_as_float(f3.x & 0xffff0000u);
    b2 += w3 * __uint_as_float(f3.y << 16);
    b3 += w3 * __uint_as_float(f3.y & 0xffff0000u);
    a0 += w4 * __uint_as_float(f4.x << 16);
    a1 += w4 * __uint_as_float(f4.x & 0xffff0000u);
    a2 += w4 * __uint_as_float(f4.y << 16);
    a3 += w4 * __uint_as_float(f4.y & 0xffff0000u);
    b0 += w5 * __uint_as_float(f5.x << 16);
    b1 += w5 * __uint_as_float(f5.x & 0xffff0000u);
    b2 += w5 * __uint_as_float(f5.y << 16);
    b3 += w5 * __uint_as_float(f5.y & 0xffff0000u);
    a0 += w6 * __uint_as_float(f6.x << 16);
    a1 += w6 * __uint_as_float(f6.x & 0xffff0000u);
    a2 += w6 * __uint_as_float(f6.y << 16);
    a3 += w6 * __uint_as_float(f6.y & 0xffff0000u);
    b0 += w7 * __uint_as_float(f7.x << 16);
    b1 += w7 * __uint_as_float(f7.x & 0xffff0000u);
    b2 += w7 * __uint_as_float(f7.y << 16);
    b3 += w7 * __uint_as_float(f7.y & 0xffff0000u);
  }
  for (; p + 3 < cnt; p += 4) {
    int e0 = start + p;
    int s0 = csr_src[e0], s1 = csr_src[e0 + 1], s2 = csr_src[e0 + 2], s3 = csr_src[e0 + 3];
    float w0 = alpha[(size_t)(e0    ) * 4 + head];
    float w1 = alpha[(size_t)(e0 + 1) * 4 + head];
    float w2 = alpha[(size_t)(e0 + 2) * 4 + head];
    float w3 = alpha[(size_t)(e0 + 3) * 4 + head];
    uint2v f0 = *reinterpret_cast<const uint2v*>(Fh + (size_t)s0 * 256 + lane * 4);
    uint2v f1 = *reinterpret_cast<const uint2v*>(Fh + (size_t)s1 * 256 + lane * 4);
    uint2v f2 = *reinterpret_cast<const uint2v*>(Fh + (size_t)s2 * 256 + lane * 4);
    uint2v f3 = *reinterpret_cast<const uint2v*>(Fh + (size_t)s3 * 256 + lane * 4);
    a0 += w0 * __uint_as_float(f0.x << 16);
    a1 += w0 * __uint_as_float(f0.x & 0xffff0000u);
    a2 += w0 * __uint_as_float(f0.y << 16);
    a3 += w0 * __uint_as_float(f0.y & 0xffff0000u);
    b0 += w1 * __uint_as_float(f1.x << 16);
    b1 += w1 * __uint_as_float(f1.x & 0xffff0000u);
    b2 += w1 * __uint_as_float(f1.y << 16);
    b3 += w1 * __uint_as_float(f1.y & 0xffff0000u);
    a0 += w2 * __uint_as_float(f2.x << 16);
    a1 += w2 * __uint_as_float(f2.x & 0xffff0000u);
    a2 += w2 * __uint_as_float(f2.y << 16);
    a3 += w2 * __uint_as_float(f2.y & 0xffff0000u);
    b0 += w3 * __uint_as_float(f3.x << 16);
    b1 += w3 * __uint_as_float(f3.x & 0xffff0000u);
    b2 += w3 * __uint_as_float(f3.y << 16);
    b3 += w3 * __uint_as_float(f3.y & 0xffff0000u);
  }
  for (; p < cnt; ++p) {
    int e0 = start + p;
    int s0 = csr_src[e0];
    float w0 = alpha[(size_t)e0 * 4 + head];
    uint2v f0 = *reinterpret_cast<const uint2v*>(Fh + (size_t)s0 * 256 + lane * 4);
    a0 += w0 * __uint_as_float(f0.x << 16);
    a1 += w0 * __uint_as_float(f0.x & 0xffff0000u);
    a2 += w0 * __uint_as_float(f0.y << 16);
    a3 += w0 * __uint_as_float(f0.y & 0xffff0000u);
  }
  a0 += b0; a1 += b1; a2 += b2; a3 += b3;
  // epilogue: bias + ELU + hi/lo split, packed 8B stores
  floatx4 bv = *reinterpret_cast<const floatx4*>(bias + lane * 4);
  float o0 = a0 + bv.x, o1 = a1 + bv.y, o2 = a2 + bv.z, o3 = a3 + bv.w;
  o0 = o0 > 0.f ? o0 : __expf(o0) - 1.f;
  o1 = o1 > 0.f ? o1 : __expf(o1) - 1.f;
  o2 = o2 > 0.f ? o2 : __expf(o2) - 1.f;
  o3 = o3 > 0.f ? o3 : __expf(o3) - 1.f;
  float h0 = bf2f(f2bf(o0)), h1 = bf2f(f2bf(o1)), h2 = bf2f(f2bf(o2)), h3 = bf2f(f2bf(o3));
  short4v hv = (short4v){(short)bfbits(o0), (short)bfbits(o1), (short)bfbits(o2), (short)bfbits(o3)};
  short4v lv = (short4v){(short)bfbits(o0 - h0), (short)bfbits(o1 - h1),
                         (short)bfbits(o2 - h2), (short)bfbits(o3 - h3)};
  *reinterpret_cast<short4v*>(Oh + (size_t)dst * 256 + lane * 4) = hv;
  *reinterpret_cast<short4v*>(Ol + (size_t)dst * 256 + lane * 4) = lv;
}

// ---------------- aggregation, final layer (64-pad feat, 47 out, fp32) ------
__global__ void agg_final_kernel(const int* __restrict__ row_ptr,
                                 const int* __restrict__ csr_src,
                                 const __hip_bfloat16* __restrict__ Fh,
                                 const float* __restrict__ alpha,
                                 const float* __restrict__ bias,
                                 float* __restrict__ out) {
  int wid = threadIdx.x >> 6, lane = threadIdx.x & 63;
  int dst = blockIdx.x * 4 + wid;
  if (dst >= NNODES) return;
  int start = row_ptr[dst], end = row_ptr[dst + 1];
  int cnt = end - start;
  float acc = 0.f, acc2 = 0.f;
  int p = 0;
  for (; p + 7 < cnt; p += 8) {
    int e0 = start + p;
    int s0 = csr_src[e0],     s1 = csr_src[e0 + 1], s2 = csr_src[e0 + 2], s3 = csr_src[e0 + 3];
    int s4 = csr_src[e0 + 4], s5 = csr_src[e0 + 5], s6 = csr_src[e0 + 6], s7 = csr_src[e0 + 7];
    float w0 = alpha[e0],     w1 = alpha[e0 + 1], w2 = alpha[e0 + 2], w3 = alpha[e0 + 3];
    float w4 = alpha[e0 + 4], w5 = alpha[e0 + 5], w6 = alpha[e0 + 6], w7 = alpha[e0 + 7];
    float f0 = bf2f(Fh[(size_t)s0 * 64 + lane]);
    float f1 = bf2f(Fh[(size_t)s1 * 64 + lane]);
    float f2 = bf2f(Fh[(size_t)s2 * 64 + lane]);
    float f3 = bf2f(Fh[(size_t)s3 * 64 + lane]);
    float f4 = bf2f(Fh[(size_t)s4 * 64 + lane]);
    float f5 = bf2f(Fh[(size_t)s5 * 64 + lane]);
    float f6 = bf2f(Fh[(size_t)s6 * 64 + lane]);
    float f7 = bf2f(Fh[(size_t)s7 * 64 + lane]);
    acc  += w0 * f0 + w2 * f2 + w4 * f4 + w6 * f6;
    acc2 += w1 * f1 + w3 * f3 + w5 * f5 + w7 * f7;
  }
  for (; p < cnt; ++p) {
    int e0 = start + p;
    acc += alpha[e0] * bf2f(Fh[(size_t)csr_src[e0] * 64 + lane]);
  }
  acc += acc2;
  if (lane < 47) out[(size_t)dst * 47 + lane] = acc + bias[lane];
}

// ---------------- launch ----------------
extern "C" void kernel_launch(void* const* d_in, const int* in_sizes, int n_in,
                              void* d_out, int out_size, void* d_ws, size_t ws_size,
                              hipStream_t stream) {
  const float* x   = (const float*)d_in[0];
  const int* ei    = (const int*)d_in[1];
  const float* W1  = (const float*)d_in[2];
  const float* a1s = (const float*)d_in[3];
  const float* a1d = (const float*)d_in[4];
  const float* b1  = (const float*)d_in[5];
  const float* W2  = (const float*)d_in[6];
  const float* a2s = (const float*)d_in[7];
  const float* a2d = (const float*)d_in[8];
  const float* b2  = (const float*)d_in[9];
  const float* W3  = (const float*)d_in[10];
  const float* a3s = (const float*)d_in[11];
  const float* a3d = (const float*)d_in[12];
  const float* b3  = (const float*)d_in[13];
  float* out = (float*)d_out;
  (void)n_in; (void)in_sizes;

  char* base = (char*)d_ws;
  size_t off = 0;
  auto alloc = [&](size_t bytes) -> char* {
    off = (off + 255) & ~(size_t)255;
    char* p = base + off;
    off += bytes;
    return p;
  };
  int* deg     = (int*)alloc((size_t)NNODES * 4);
  int* cursor  = (int*)alloc((size_t)NNODES * 4);
  int* row_ptr = (int*)alloc((size_t)(NNODES + 1) * 4);
  int* csr_src = (int*)alloc((size_t)ETOT * 4);
  int* tmp_src = (int*)alloc((size_t)ETOT * 4);
  int* tmp_p   = (int*)alloc((size_t)ETOT * 4);
  int* bsum    = (int*)alloc(256 * 4);
  int* boff    = (int*)alloc(256 * 4);
  float* als   = (float*)alloc((size_t)NNODES * 4 * 4);
  float* ald   = (float*)alloc((size_t)NNODES * 4 * 4);
  float* alpha = (float*)alloc((size_t)ETOT * 4 * 4);
  __hip_bfloat16* Ah = (__hip_bfloat16*)alloc((size_t)MPAD * 256 * 2);
  __hip_bfloat16* Al = (__hip_bfloat16*)alloc((size_t)MPAD * 256 * 2);
  __hip_bfloat16* Fh = (__hip_bfloat16*)alloc((size_t)NNODES * 256 * 2);
  __hip_bfloat16* wth = (__hip_bfloat16*)alloc((size_t)256 * 256 * 2);
  __hip_bfloat16* wtl = (__hip_bfloat16*)alloc((size_t)256 * 256 * 2);
  float* asv3 = (float*)alloc(64 * 4);
  float* adv3 = (float*)alloc(64 * 4);

  if (ws_size < off) {
    fill_out_kernel<<<(out_size + 255) / 256, 256, 0, stream>>>(out, out_size, 12345.f);
    return;
  }

  // CSR build (deterministic): degree -> scan -> atomic scatter to temps ->
  // per-bucket canonical sort by edge index
  zero_int_kernel<<<(NNODES + 255) / 256, 256, 0, stream>>>(deg, NNODES);
  degree_kernel<<<(ETOT + 255) / 256, 256, 0, stream>>>(ei, deg);
  block_sum_kernel<<<NBLK, 256, 0, stream>>>(deg, bsum);
  scan_bsum_kernel<<<1, 256, 0, stream>>>(bsum, boff, row_ptr);
  emit_rowptr_kernel<<<NBLK, 256, 0, stream>>>(deg, boff, row_ptr, cursor);
  scatter_kernel<<<(ETOT + 255) / 256, 256, 0, stream>>>(ei, cursor, tmp_src, tmp_p);
  bucket_sort_kernel<<<(NNODES + 3) / 4, 256, 0, stream>>>(row_ptr, tmp_src, tmp_p, csr_src);

  split_input_kernel<<<(MPAD * 256 + 255) / 256, 256, 0, stream>>>(x, Ah, Al);
  pad47_kernel<<<1, 64, 0, stream>>>(a3s, a3d, asv3, adv3);

  const int grid12 = (NNODES + 63) / 64;       // 782
  const int grid3 = (NNODES + 255) / 256;      // 196
  const int gridN4 = (NNODES + 3) / 4;

  // layer 1: 128 -> 4x64, ELU
  pack_w_kernel<<<(256 * 128 + 255) / 256, 256, 0, stream>>>(W1, wth, wtl, 128, 256, 256);
  gemm_attn_kernel<128, 256, 4, 4><<<grid12, 256, 0, stream>>>(Ah, Al, wth, wtl, a1s, a1d,
                                                               Fh, als, ald);
  alpha_kernel<4><<<gridN4, 256, 0, stream>>>(row_ptr, csr_src, als, ald, alpha);
  agg_mid_kernel<<<gridN4, 256, 0, stream>>>(row_ptr, csr_src, Fh, alpha, b1, Ah, Al);

  // layer 2: 256 -> 4x64, ELU
  pack_w_kernel<<<(256 * 256 + 255) / 256, 256, 0, stream>>>(W2, wth, wtl, 256, 256, 256);
  gemm_attn_kernel<256, 256, 4, 4><<<grid12, 256, 0, stream>>>(Ah, Al, wth, wtl, a2s, a2d,
                                                               Fh, als, ald);
  alpha_kernel<4><<<gridN4, 256, 0, stream>>>(row_ptr, csr_src, als, ald, alpha);
  agg_mid_kernel<<<gridN4, 256, 0, stream>>>(row_ptr, csr_src, Fh, alpha, b2, Ah, Al);

  // layer 3: 256 -> 47 (pad 64), no ELU, fp32 out
  pack_w_kernel<<<(64 * 256 + 255) / 256, 256, 0, stream>>>(W3, wth, wtl, 256, 47, 64);
  gemm_attn_kernel<256, 64, 1, 1><<<grid3, 256, 0, stream>>>(Ah, Al, wth, wtl, asv3, adv3,
                                                             Fh, als, ald);
  alpha_kernel<1><<<gridN4, 256, 0, stream>>>(row_ptr, csr_src, als, ald, alpha);
  agg_final_kernel<<<gridN4, 256, 0, stream>>>(row_ptr, csr_src, Fh, alpha, b3, out);
}

// Round 11
// 526.859 us; speedup vs baseline: 1.0303x; 1.0303x over previous
//
#include <hip/hip_runtime.h>
#include <hip/hip_bf16.h>

#define NNODES 50000
#define NEDGES 800000
#define ETOT   (NNODES + NEDGES)
#define MTILES 3136            // row-tiles of 16: covers 50176 rows
#define MPAD   (MTILES * 16)   // 50176
#define NBLK   196             // ceil(NNODES/256) for the scan

typedef __attribute__((ext_vector_type(8))) short short8;
typedef __attribute__((ext_vector_type(4))) float floatx4;
typedef __attribute__((ext_vector_type(2))) unsigned int uint2v;
typedef __attribute__((ext_vector_type(4))) short short4v;

__device__ __forceinline__ float bf2f(__hip_bfloat16 x) { return __bfloat162float(x); }
__device__ __forceinline__ __hip_bfloat16 f2bf(float f) { return __float2bfloat16(f); }
__device__ __forceinline__ float sane(float v, float c) {
  v = (v == v) ? v : 0.f;
  return fminf(fmaxf(v, -c), c);
}
__device__ __forceinline__ unsigned short bfbits(float f) {
  union { __hip_bfloat16 b; unsigned short u; } cv;
  cv.b = f2bf(f);
  return cv.u;
}

// ---------------- utility ----------------
__global__ void zero_int_kernel(int* __restrict__ p, int n) {
  int i = blockIdx.x * blockDim.x + threadIdx.x;
  if (i < n) p[i] = 0;
}
__global__ void fill_out_kernel(float* __restrict__ o, int n, float v) {
  int i = blockIdx.x * blockDim.x + threadIdx.x;
  if (i < n) o[i] = v;
}
// split x into hi/lo bf16 (vectorized x4); zero-fill pad region
__global__ void split_input_kernel(const float* __restrict__ in,
                                   __hip_bfloat16* __restrict__ hi,
                                   __hip_bfloat16* __restrict__ lo) {
  int i = blockIdx.x * blockDim.x + threadIdx.x;  // over MPAD*64
  if (i >= MPAD * 64) return;
  floatx4 v;
  if (i < NNODES * 32) {
    v = *reinterpret_cast<const floatx4*>(in + (size_t)i * 4);
    v.x = sane(v.x, 1e4f); v.y = sane(v.y, 1e4f);
    v.z = sane(v.z, 1e4f); v.w = sane(v.w, 1e4f);
  } else {
    v = (floatx4){0.f, 0.f, 0.f, 0.f};
  }
  float h0 = bf2f(f2bf(v.x)), h1 = bf2f(f2bf(v.y)), h2 = bf2f(f2bf(v.z)), h3 = bf2f(f2bf(v.w));
  short4v hv = (short4v){(short)bfbits(v.x), (short)bfbits(v.y),
                         (short)bfbits(v.z), (short)bfbits(v.w)};
  short4v lv = (short4v){(short)bfbits(v.x - h0), (short)bfbits(v.y - h1),
                         (short)bfbits(v.z - h2), (short)bfbits(v.w - h3)};
  *reinterpret_cast<short4v*>(hi + (size_t)i * 4) = hv;
  *reinterpret_cast<short4v*>(lo + (size_t)i * 4) = lv;
}
// pad 47-vec attention params to 64 with zeros
__global__ void pad47_kernel(const float* __restrict__ a, const float* __restrict__ b,
                             float* __restrict__ ap, float* __restrict__ bp) {
  int i = threadIdx.x;  // 64
  ap[i] = (i < 47) ? sane(a[i], 1e4f) : 0.f;
  bp[i] = (i < 47) ? sane(b[i], 1e4f) : 0.f;
}

// ---------------- CSR build (dst-sorted, DETERMINISTIC) ----------------
__global__ void degree_kernel(const int* __restrict__ ei, int* __restrict__ deg) {
  int p = blockIdx.x * blockDim.x + threadIdx.x;
  if (p >= ETOT) return;
  int dst = (p < NEDGES) ? ei[NEDGES + p] : (p - NEDGES);
  dst = min(max(dst, 0), NNODES - 1);
  atomicAdd(&deg[dst], 1);
}

// --- parallel 3-phase scan ---
__global__ __launch_bounds__(256) void block_sum_kernel(const int* __restrict__ deg,
                                                        int* __restrict__ bsum) {
  __shared__ int sh[256];
  int b = blockIdx.x, t = threadIdx.x;
  int i = b * 256 + t;
  sh[t] = (i < NNODES) ? deg[i] : 0;
  __syncthreads();
  for (int off = 128; off > 0; off >>= 1) {
    if (t < off) sh[t] += sh[t + off];
    __syncthreads();
  }
  if (t == 0) bsum[b] = sh[0];
}

__global__ __launch_bounds__(256) void scan_bsum_kernel(const int* __restrict__ bsum,
                                                        int* __restrict__ boff,
                                                        int* __restrict__ row_ptr) {
  __shared__ int sh[256];
  int t = threadIdx.x;
  int v = (t < NBLK) ? bsum[t] : 0;
  sh[t] = v;
  __syncthreads();
  for (int off = 1; off < 256; off <<= 1) {
    int u = (t >= off) ? sh[t - off] : 0;
    __syncthreads();
    sh[t] += u;
    __syncthreads();
  }
  if (t < NBLK) boff[t] = sh[t] - v;  // exclusive block offset
  if (t == 255) row_ptr[NNODES] = sh[255];
}

__global__ __launch_bounds__(256) void emit_rowptr_kernel(const int* __restrict__ deg,
                                                          const int* __restrict__ boff,
                                                          int* __restrict__ row_ptr,
                                                          int* __restrict__ cursor) {
  __shared__ int sh[256];
  int b = blockIdx.x, t = threadIdx.x;
  int i = b * 256 + t;
  int d = (i < NNODES) ? deg[i] : 0;
  sh[t] = d;
  __syncthreads();
  for (int off = 1; off < 256; off <<= 1) {
    int u = (t >= off) ? sh[t - off] : 0;
    __syncthreads();
    sh[t] += u;
    __syncthreads();
  }
  if (i < NNODES) {
    int v = boff[b] + sh[t] - d;  // exclusive prefix
    row_ptr[i] = v;
    cursor[i] = v;
  }
}

// scatter into TEMP arrays (atomic positions; order repaired by bucket sort)
__global__ void scatter_kernel(const int* __restrict__ ei, int* __restrict__ cursor,
                               int* __restrict__ tmp_src, int* __restrict__ tmp_p) {
  int p = blockIdx.x * blockDim.x + threadIdx.x;
  if (p >= ETOT) return;
  int src, dst;
  if (p < NEDGES) { src = ei[p]; dst = ei[NEDGES + p]; }
  else            { src = p - NEDGES; dst = src; }
  src = min(max(src, 0), NNODES - 1);
  dst = min(max(dst, 0), NNODES - 1);
  int pos = atomicAdd(&cursor[dst], 1);
  pos = min(max(pos, 0), ETOT - 1);
  tmp_src[pos] = src;
  tmp_p[pos] = p;
}

// canonicalize each dst bucket by original edge index p (all p distinct ->
// rank is an exact permutation). Makes csr_src deterministic.
__global__ __launch_bounds__(256) void bucket_sort_kernel(const int* __restrict__ row_ptr,
                                                          const int* __restrict__ tmp_src,
                                                          const int* __restrict__ tmp_p,
                                                          int* __restrict__ csr_src) {
  int wid = threadIdx.x >> 6, lane = threadIdx.x & 63;
  int dst = blockIdx.x * 4 + wid;
  if (dst >= NNODES) return;
  int start = row_ptr[dst], end = row_ptr[dst + 1];
  int cnt = end - start;
  for (int i = lane; i < cnt; i += 64) {
    int pi = tmp_p[start + i];
    int si = tmp_src[start + i];
    int rank = 0;
    for (int j = 0; j < cnt; ++j) rank += (tmp_p[start + j] < pi) ? 1 : 0;
    csr_src[start + rank] = si;
  }
}

// ---------------- weight pack (W [K][Nreal] f32 -> fragment-packed W^T) -------
__global__ void pack_w_kernel(const float* __restrict__ W,
                              __hip_bfloat16* __restrict__ Bh,
                              __hip_bfloat16* __restrict__ Bl,
                              int K, int Nreal, int Npad) {
  int idx = blockIdx.x * blockDim.x + threadIdx.x;
  if (idx >= Npad * K) return;
  int e = idx;
  int j = e & 7;    e >>= 3;
  int m = e & 15;   e >>= 4;
  int quad = e & 3; e >>= 2;
  int kch = K >> 5;
  int kk32 = e % kch;
  int nt = e / kch;
  int n = nt * 16 + m;
  int k = kk32 * 32 + quad * 8 + j;
  float v = (n < Nreal) ? sane(W[k * Nreal + n], 1e4f) : 0.f;
  __hip_bfloat16 h = f2bf(v);
  Bh[idx] = h;
  Bl[idx] = f2bf(v - bf2f(h));
}

// ---------------- GEMM + fused attention logits (verified bit-exact) --------
template<int KDIM, int NOUT, int HEADS, int WAVES_N>
__global__ __launch_bounds__(256) void gemm_attn_kernel(
    const __hip_bfloat16* __restrict__ Ah, const __hip_bfloat16* __restrict__ Al,
    const __hip_bfloat16* __restrict__ Bh, const __hip_bfloat16* __restrict__ Bl,
    const float* __restrict__ asv, const float* __restrict__ adv,
    __hip_bfloat16* __restrict__ Ch, float* __restrict__ als, float* __restrict__ ald) {
  constexpr int KCH = KDIM / 32;
  constexpr int CT = (NOUT / 16) / WAVES_N;  // 4
  constexpr int RT = 4;
  constexpr int RGROUPS = 4 / WAVES_N;       // row groups per block
  __shared__ __hip_bfloat16 sAh[2 * 64 * 32];
  __shared__ __hip_bfloat16 sAl[2 * 64 * 32];
  int wave = threadIdx.x >> 6, lane = threadIdx.x & 63;
  int wrow = wave / WAVES_N, wcol = wave % WAVES_N;
  int rt0 = (blockIdx.x * RGROUPS + wrow) * RT;
  int ct0 = wcol * CT;
  int m = lane & 15, quad = lane >> 4;

  const short8* Bph = reinterpret_cast<const short8*>(Bh);
  const short8* Bpl = reinterpret_cast<const short8*>(Bl);

  floatx4 acc[RT][CT];
#pragma unroll
  for (int rt = 0; rt < RT; ++rt)
#pragma unroll
    for (int ct = 0; ct < CT; ++ct) acc[rt][ct] = (floatx4){0.f, 0.f, 0.f, 0.f};

  int tid = threadIdx.x;
  size_t gstage = (size_t)(rt0 * 16 + (tid >> 2)) * KDIM + (tid & 3) * 8;

#pragma unroll 2
  for (int ks = 0; ks < KCH / 2; ++ks) {
    short8 a_h[RT], a_l[RT];
    if constexpr (WAVES_N == 4) {
      // stage slices 2ks and 2ks+1 together
      short8 vh0 = *reinterpret_cast<const short8*>(Ah + gstage + ks * 64);
      short8 vh1 = *reinterpret_cast<const short8*>(Ah + gstage + ks * 64 + 32);
      short8 vl0 = *reinterpret_cast<const short8*>(Al + gstage + ks * 64);
      short8 vl1 = *reinterpret_cast<const short8*>(Al + gstage + ks * 64 + 32);
      __syncthreads();  // prior stage's reads complete before overwrite
      *reinterpret_cast<short8*>(&sAh[tid * 8]) = vh0;
      *reinterpret_cast<short8*>(&sAh[2048 + tid * 8]) = vh1;
      *reinterpret_cast<short8*>(&sAl[tid * 8]) = vl0;
      *reinterpret_cast<short8*>(&sAl[2048 + tid * 8]) = vl1;
      __syncthreads();
#pragma unroll
      for (int kk0 = 0; kk0 < 2; ++kk0) {
#pragma unroll
        for (int rt = 0; rt < RT; ++rt) {
          int so = kk0 * 2048 + (rt * 16 + m) * 32 + quad * 8;
          a_h[rt] = *reinterpret_cast<const short8*>(&sAh[so]);
          a_l[rt] = *reinterpret_cast<const short8*>(&sAl[so]);
        }
        int kk = ks * 2 + kk0;
#pragma unroll
        for (int ct = 0; ct < CT; ++ct) {
          size_t o = ((size_t)(ct0 + ct) * KCH + kk) * 64 + lane;
          short8 b_h = Bph[o];
          short8 b_l = Bpl[o];
#pragma unroll
          for (int rt = 0; rt < RT; ++rt) {
            acc[rt][ct] = __builtin_amdgcn_mfma_f32_16x16x32_bf16(a_h[rt], b_h, acc[rt][ct], 0, 0, 0);
            acc[rt][ct] = __builtin_amdgcn_mfma_f32_16x16x32_bf16(a_h[rt], b_l, acc[rt][ct], 0, 0, 0);
            acc[rt][ct] = __builtin_amdgcn_mfma_f32_16x16x32_bf16(a_l[rt], b_h, acc[rt][ct], 0, 0, 0);
          }
        }
      }
    } else {
#pragma unroll
      for (int kk0 = 0; kk0 < 2; ++kk0) {
        int kk = ks * 2 + kk0;
#pragma unroll
        for (int rt = 0; rt < RT; ++rt) {
          size_t aoff = (size_t)((rt0 + rt) * 16 + m) * KDIM + kk * 32 + quad * 8;
          a_h[rt] = *reinterpret_cast<const short8*>(Ah + aoff);
          a_l[rt] = *reinterpret_cast<const short8*>(Al + aoff);
        }
#pragma unroll
        for (int ct = 0; ct < CT; ++ct) {
          size_t o = ((size_t)(ct0 + ct) * KCH + kk) * 64 + lane;
          short8 b_h = Bph[o];
          short8 b_l = Bpl[o];
#pragma unroll
          for (int rt = 0; rt < RT; ++rt) {
            acc[rt][ct] = __builtin_amdgcn_mfma_f32_16x16x32_bf16(a_h[rt], b_h, acc[rt][ct], 0, 0, 0);
            acc[rt][ct] = __builtin_amdgcn_mfma_f32_16x16x32_bf16(a_h[rt], b_l, acc[rt][ct], 0, 0, 0);
            acc[rt][ct] = __builtin_amdgcn_mfma_f32_16x16x32_bf16(a_l[rt], b_h, acc[rt][ct], 0, 0, 0);
          }
        }
      }
    }
  }

  // fused attention logits: this wave's CT*16 cols lie in exactly one head
  constexpr int CPH = NOUT / HEADS;
  int head = (ct0 * 16) / CPH;
  float asl[CT], adl[CT];
#pragma unroll
  for (int ct = 0; ct < CT; ++ct) {
    asl[ct] = asv[(ct0 + ct) * 16 + m];
    adl[ct] = adv[(ct0 + ct) * 16 + m];
  }
  float ps[RT * 4], pd[RT * 4];
#pragma unroll
  for (int i = 0; i < RT * 4; ++i) { ps[i] = 0.f; pd[i] = 0.f; }
#pragma unroll
  for (int rt = 0; rt < RT; ++rt)
#pragma unroll
    for (int ct = 0; ct < CT; ++ct)
#pragma unroll
      for (int r = 0; r < 4; ++r) {
        ps[rt * 4 + r] += acc[rt][ct][r] * asl[ct];
        pd[rt * 4 + r] += acc[rt][ct][r] * adl[ct];
      }
#pragma unroll
  for (int off = 1; off < 16; off <<= 1) {
#pragma unroll
    for (int i = 0; i < RT * 4; ++i) {
      ps[i] += __shfl_xor(ps[i], off);
      pd[i] += __shfl_xor(pd[i], off);
    }
  }
  if (m == 0) {
#pragma unroll
    for (int rt = 0; rt < RT; ++rt)
#pragma unroll
      for (int r = 0; r < 4; ++r) {
        int row = (rt0 + rt) * 16 + quad * 4 + r;
        if (row < NNODES) {
          als[(size_t)row * HEADS + head] = sane(ps[rt * 4 + r], 80.f);
          ald[(size_t)row * HEADS + head] = sane(pd[rt * 4 + r], 80.f);
        }
      }
  }

  // store C (hi-only bf16, row-major for the aggregation gather)
#pragma unroll
  for (int rt = 0; rt < RT; ++rt)
#pragma unroll
    for (int ct = 0; ct < CT; ++ct)
#pragma unroll
      for (int r = 0; r < 4; ++r) {
        int row = (rt0 + rt) * 16 + quad * 4 + r;
        if (row < NNODES) {
          float v = sane(acc[rt][ct][r], 3e4f);
          Ch[(size_t)row * NOUT + (ct0 + ct) * 16 + m] = f2bf(v);
        }
      }
}

// ---------------- normalized edge weights, H=4 (grouped) ----------------
// wave per dst; each 16-lane group owns one head; lanes cover 16 edges/pass.
// Up to 64 edges held in registers (single write pass); rare overflow path
// stores unnormalized then scales in-place. Deterministic (fixed reduce tree).
__global__ __launch_bounds__(256) void alpha4_kernel(const int* __restrict__ row_ptr,
                                                     const int* __restrict__ csr_src,
                                                     const float* __restrict__ als,
                                                     const float* __restrict__ ald,
                                                     float* __restrict__ alpha) {
  int wid = threadIdx.x >> 6, lane = threadIdx.x & 63;
  int dst = blockIdx.x * 4 + wid;
  if (dst >= NNODES) return;
  int start = row_ptr[dst], end = row_ptr[dst + 1];
  int cnt = end - start;
  if (cnt <= 0) return;
  int g = lane >> 4, cl = lane & 15;
  float adh = ald[(size_t)dst * 4 + g];
  float dl = 0.f;
  float wreg[4];
#pragma unroll
  for (int k = 0; k < 4; ++k) {
    int i = cl + k * 16;
    if (i < cnt) {
      int s = min(max(csr_src[start + i], 0), NNODES - 1);
      float e = als[(size_t)s * 4 + g] + adh;
      e = e > 0.f ? e : 0.2f * e;
      e = fminf(fmaxf(e, -80.f), 80.f);
      float w = __expf(e);
      wreg[k] = w;
      dl += w;
    }
  }
  for (int i = cl + 64; i < cnt; i += 16) {  // rare: deg > 64
    int s = min(max(csr_src[start + i], 0), NNODES - 1);
    float e = als[(size_t)s * 4 + g] + adh;
    e = e > 0.f ? e : 0.2f * e;
    e = fminf(fmaxf(e, -80.f), 80.f);
    float w = __expf(e);
    alpha[(size_t)(start + i) * 4 + g] = w;
    dl += w;
  }
#pragma unroll
  for (int off = 1; off < 16; off <<= 1) dl += __shfl_xor(dl, off);
  float inv = 1.f / fmaxf(dl, 1e-30f);
#pragma unroll
  for (int k = 0; k < 4; ++k) {
    int i = cl + k * 16;
    if (i < cnt) alpha[(size_t)(start + i) * 4 + g] = wreg[k] * inv;
  }
  for (int i = cl + 64; i < cnt; i += 16)
    alpha[(size_t)(start + i) * 4 + g] *= inv;
}

// ---------------- normalized edge weights, H=1 (layer 3) ----------------
__global__ __launch_bounds__(256) void alpha1_kernel(const int* __restrict__ row_ptr,
                                                     const int* __restrict__ csr_src,
                                                     const float* __restrict__ als,
                                                     const float* __restrict__ ald,
                                                     float* __restrict__ alpha) {
  int wid = threadIdx.x >> 6, lane = threadIdx.x & 63;
  int dst = blockIdx.x * 4 + wid;
  if (dst >= NNODES) return;
  int start = row_ptr[dst], end = row_ptr[dst + 1];
  int cnt = end - start;
  if (cnt <= 0) return;
  float adh = ald[dst];
  if (cnt <= 64) {
    int i = start + lane;
    bool valid = lane < cnt;
    int s = valid ? min(max(csr_src[i], 0), NNODES - 1) : 0;
    float e = als[s] + adh;
    e = e > 0.f ? e : 0.2f * e;
    e = fminf(fmaxf(e, -80.f), 80.f);
    float w = valid ? __expf(e) : 0.f;
    float v = w;
#pragma unroll
    for (int off = 1; off < 64; off <<= 1) v += __shfl_xor(v, off);
    float inv = 1.f / fmaxf(v, 1e-30f);
    if (valid) alpha[i] = w * inv;
  } else {
    float dlsum = 0.f;
    for (int base = start; base < end; base += 64) {
      int i = base + lane;
      bool valid = i < end;
      int s = valid ? min(max(csr_src[i], 0), NNODES - 1) : 0;
      float e = als[s] + adh;
      e = e > 0.f ? e : 0.2f * e;
      e = fminf(fmaxf(e, -80.f), 80.f);
      float w = valid ? __expf(e) : 0.f;
      dlsum += w;
      if (valid) alpha[i] = w;
    }
#pragma unroll
    for (int off = 1; off < 64; off <<= 1) dlsum += __shfl_xor(dlsum, off);
    float inv = 1.f / fmaxf(dlsum, 1e-30f);
    for (int base = start; base < end; base += 64) {
      int i = base + lane;
      if (i < end) alpha[i] *= inv;
    }
  }
}

// ---------------- aggregation, mid layers (T=256, H=4) ----------------
// ONE WAVE PER DST (R8 measured-best form); lane owns 4 cols (uint2 8B load);
// 4 edges in flight; no LDS, no barriers; register epilogue.
__global__ __launch_bounds__(256) void agg_mid_kernel(const int* __restrict__ row_ptr,
                                                      const int* __restrict__ csr_src,
                                                      const __hip_bfloat16* __restrict__ Fh,
                                                      const float* __restrict__ alpha,
                                                      const float* __restrict__ bias,
                                                      __hip_bfloat16* __restrict__ Oh,
                                                      __hip_bfloat16* __restrict__ Ol) {
  int wid = threadIdx.x >> 6, lane = threadIdx.x & 63;
  int dst = blockIdx.x * 4 + wid;
  if (dst >= NNODES) return;
  int start = row_ptr[dst], end = row_ptr[dst + 1];
  int cnt = end - start;
  int head = lane >> 4;
  float a0 = 0.f, a1 = 0.f, a2 = 0.f, a3 = 0.f;
  int p = 0;
  for (; p + 3 < cnt; p += 4) {  // 4 edges in flight
    int e0 = start + p, e1 = e0 + 1, e2 = e0 + 2, e3 = e0 + 3;
    int s0 = csr_src[e0], s1 = csr_src[e1], s2 = csr_src[e2], s3 = csr_src[e3];
    float w0 = alpha[(size_t)e0 * 4 + head];
    float w1 = alpha[(size_t)e1 * 4 + head];
    float w2 = alpha[(size_t)e2 * 4 + head];
    float w3 = alpha[(size_t)e3 * 4 + head];
    uint2v f0 = *reinterpret_cast<const uint2v*>(Fh + (size_t)s0 * 256 + lane * 4);
    uint2v f1 = *reinterpret_cast<const uint2v*>(Fh + (size_t)s1 * 256 + lane * 4);
    uint2v f2 = *reinterpret_cast<const uint2v*>(Fh + (size_t)s2 * 256 + lane * 4);
    uint2v f3 = *reinterpret_cast<const uint2v*>(Fh + (size_t)s3 * 256 + lane * 4);
    a0 += w0 * __uint_as_float(f0.x << 16);
    a1 += w0 * __uint_as_float(f0.x & 0xffff0000u);
    a2 += w0 * __uint_as_float(f0.y << 16);
    a3 += w0 * __uint_as_float(f0.y & 0xffff0000u);
    a0 += w1 * __uint_as_float(f1.x << 16);
    a1 += w1 * __uint_as_float(f1.x & 0xffff0000u);
    a2 += w1 * __uint_as_float(f1.y << 16);
    a3 += w1 * __uint_as_float(f1.y & 0xffff0000u);
    a0 += w2 * __uint_as_float(f2.x << 16);
    a1 += w2 * __uint_as_float(f2.x & 0xffff0000u);
    a2 += w2 * __uint_as_float(f2.y << 16);
    a3 += w2 * __uint_as_float(f2.y & 0xffff0000u);
    a0 += w3 * __uint_as_float(f3.x << 16);
    a1 += w3 * __uint_as_float(f3.x & 0xffff0000u);
    a2 += w3 * __uint_as_float(f3.y << 16);
    a3 += w3 * __uint_as_float(f3.y & 0xffff0000u);
  }
  for (; p < cnt; ++p) {
    int e0 = start + p;
    int s0 = csr_src[e0];
    float w0 = alpha[(size_t)e0 * 4 + head];
    uint2v f0 = *reinterpret_cast<const uint2v*>(Fh + (size_t)s0 * 256 + lane * 4);
    a0 += w0 * __uint_as_float(f0.x << 16);
    a1 += w0 * __uint_as_float(f0.x & 0xffff0000u);
    a2 += w0 * __uint_as_float(f0.y << 16);
    a3 += w0 * __uint_as_float(f0.y & 0xffff0000u);
  }
  // epilogue: bias + ELU + hi/lo split, packed 8B stores
  floatx4 bv = *reinterpret_cast<const floatx4*>(bias + lane * 4);
  float o0 = a0 + bv.x, o1 = a1 + bv.y, o2 = a2 + bv.z, o3 = a3 + bv.w;
  o0 = o0 > 0.f ? o0 : __expf(o0) - 1.f;
  o1 = o1 > 0.f ? o1 : __expf(o1) - 1.f;
  o2 = o2 > 0.f ? o2 : __expf(o2) - 1.f;
  o3 = o3 > 0.f ? o3 : __expf(o3) - 1.f;
  float h0 = bf2f(f2bf(o0)), h1 = bf2f(f2bf(o1)), h2 = bf2f(f2bf(o2)), h3 = bf2f(f2bf(o3));
  short4v hv = (short4v){(short)bfbits(o0), (short)bfbits(o1), (short)bfbits(o2), (short)bfbits(o3)};
  short4v lv = (short4v){(short)bfbits(o0 - h0), (short)bfbits(o1 - h1),
                         (short)bfbits(o2 - h2), (short)bfbits(o3 - h3)};
  *reinterpret_cast<short4v*>(Oh + (size_t)dst * 256 + lane * 4) = hv;
  *reinterpret_cast<short4v*>(Ol + (size_t)dst * 256 + lane * 4) = lv;
}

// ---------------- aggregation, final layer (64-pad feat, 47 out, fp32) ------
// half-wave per edge: lane owns 2 cols (one uint 4B load -> 128B/half-wave
// covers the row); halves stride edges; shfl_xor(32) combine; 2-deep unroll.
__global__ void agg_final_kernel(const int* __restrict__ row_ptr,
                                 const int* __restrict__ csr_src,
                                 const __hip_bfloat16* __restrict__ Fh,
                                 const float* __restrict__ alpha,
                                 const float* __restrict__ bias,
                                 float* __restrict__ out) {
  int wid = threadIdx.x >> 6, lane = threadIdx.x & 63;
  int dst = blockIdx.x * 4 + wid;
  if (dst >= NNODES) return;
  int start = row_ptr[dst], end = row_ptr[dst + 1];
  int cnt = end - start;
  int half = lane >> 5, cl = lane & 31;
  float acc0 = 0.f, acc1 = 0.f;
  int p = half;
  for (; p + 2 < cnt; p += 4) {  // 2 edges per half in flight (4/wave)
    int e0 = start + p, e1 = start + p + 2;
    int s0 = csr_src[e0], s1 = csr_src[e1];
    float w0 = alpha[e0], w1 = alpha[e1];
    unsigned int f0 = *reinterpret_cast<const unsigned int*>(Fh + (size_t)s0 * 64 + cl * 2);
    unsigned int f1 = *reinterpret_cast<const unsigned int*>(Fh + (size_t)s1 * 64 + cl * 2);
    acc0 += w0 * __uint_as_float(f0 << 16);
    acc1 += w0 * __uint_as_float(f0 & 0xffff0000u);
    acc0 += w1 * __uint_as_float(f1 << 16);
    acc1 += w1 * __uint_as_float(f1 & 0xffff0000u);
  }
  for (; p < cnt; p += 2) {
    int e0 = start + p;
    int s0 = csr_src[e0];
    float w0 = alpha[e0];
    unsigned int f0 = *reinterpret_cast<const unsigned int*>(Fh + (size_t)s0 * 64 + cl * 2);
    acc0 += w0 * __uint_as_float(f0 << 16);
    acc1 += w0 * __uint_as_float(f0 & 0xffff0000u);
  }
  acc0 += __shfl_xor(acc0, 32);
  acc1 += __shfl_xor(acc1, 32);
  if (half == 0) {
    int c0 = cl * 2, c1 = cl * 2 + 1;
    if (c0 < 47) out[(size_t)dst * 47 + c0] = acc0 + bias[c0];
    if (c1 < 47) out[(size_t)dst * 47 + c1] = acc1 + bias[c1];
  }
}

// ---------------- launch ----------------
extern "C" void kernel_launch(void* const* d_in, const int* in_sizes, int n_in,
                              void* d_out, int out_size, void* d_ws, size_t ws_size,
                              hipStream_t stream) {
  const float* x   = (const float*)d_in[0];
  const int* ei    = (const int*)d_in[1];
  const float* W1  = (const float*)d_in[2];
  const float* a1s = (const float*)d_in[3];
  const float* a1d = (const float*)d_in[4];
  const float* b1  = (const float*)d_in[5];
  const float* W2  = (const float*)d_in[6];
  const float* a2s = (const float*)d_in[7];
  const float* a2d = (const float*)d_in[8];
  const float* b2  = (const float*)d_in[9];
  const float* W3  = (const float*)d_in[10];
  const float* a3s = (const float*)d_in[11];
  const float* a3d = (const float*)d_in[12];
  const float* b3  = (const float*)d_in[13];
  float* out = (float*)d_out;
  (void)n_in; (void)in_sizes;

  char* base = (char*)d_ws;
  size_t off = 0;
  auto alloc = [&](size_t bytes) -> char* {
    off = (off + 255) & ~(size_t)255;
    char* p = base + off;
    off += bytes;
    return p;
  };
  int* deg     = (int*)alloc((size_t)NNODES * 4);
  int* cursor  = (int*)alloc((size_t)NNODES * 4);
  int* row_ptr = (int*)alloc((size_t)(NNODES + 1) * 4);
  int* csr_src = (int*)alloc((size_t)ETOT * 4);
  int* tmp_src = (int*)alloc((size_t)ETOT * 4);
  int* tmp_p   = (int*)alloc((size_t)ETOT * 4);
  int* bsum    = (int*)alloc(256 * 4);
  int* boff    = (int*)alloc(256 * 4);
  float* als   = (float*)alloc((size_t)NNODES * 4 * 4);
  float* ald   = (float*)alloc((size_t)NNODES * 4 * 4);
  float* alpha = (float*)alloc((size_t)ETOT * 4 * 4);
  __hip_bfloat16* Ah = (__hip_bfloat16*)alloc((size_t)MPAD * 256 * 2);
  __hip_bfloat16* Al = (__hip_bfloat16*)alloc((size_t)MPAD * 256 * 2);
  __hip_bfloat16* Fh = (__hip_bfloat16*)alloc((size_t)NNODES * 256 * 2);
  __hip_bfloat16* wth = (__hip_bfloat16*)alloc((size_t)256 * 256 * 2);
  __hip_bfloat16* wtl = (__hip_bfloat16*)alloc((size_t)256 * 256 * 2);
  float* asv3 = (float*)alloc(64 * 4);
  float* adv3 = (float*)alloc(64 * 4);

  if (ws_size < off) {
    fill_out_kernel<<<(out_size + 255) / 256, 256, 0, stream>>>(out, out_size, 12345.f);
    return;
  }

  // CSR build (deterministic): degree -> scan -> atomic scatter to temps ->
  // per-bucket canonical sort by edge index
  zero_int_kernel<<<(NNODES + 255) / 256, 256, 0, stream>>>(deg, NNODES);
  degree_kernel<<<(ETOT + 255) / 256, 256, 0, stream>>>(ei, deg);
  block_sum_kernel<<<NBLK, 256, 0, stream>>>(deg, bsum);
  scan_bsum_kernel<<<1, 256, 0, stream>>>(bsum, boff, row_ptr);
  emit_rowptr_kernel<<<NBLK, 256, 0, stream>>>(deg, boff, row_ptr, cursor);
  scatter_kernel<<<(ETOT + 255) / 256, 256, 0, stream>>>(ei, cursor, tmp_src, tmp_p);
  bucket_sort_kernel<<<(NNODES + 3) / 4, 256, 0, stream>>>(row_ptr, tmp_src, tmp_p, csr_src);

  split_input_kernel<<<(MPAD * 64 + 255) / 256, 256, 0, stream>>>(x, Ah, Al);
  pad47_kernel<<<1, 64, 0, stream>>>(a3s, a3d, asv3, adv3);

  const int grid12 = (NNODES + 63) / 64;       // 782
  const int grid3 = (NNODES + 255) / 256;      // 196
  const int gridN4 = (NNODES + 3) / 4;

  // layer 1: 128 -> 4x64, ELU
  pack_w_kernel<<<(256 * 128 + 255) / 256, 256, 0, stream>>>(W1, wth, wtl, 128, 256, 256);
  gemm_attn_kernel<128, 256, 4, 4><<<grid12, 256, 0, stream>>>(Ah, Al, wth, wtl, a1s, a1d,
                                                               Fh, als, ald);
  alpha4_kernel<<<gridN4, 256, 0, stream>>>(row_ptr, csr_src, als, ald, alpha);
  agg_mid_kernel<<<gridN4, 256, 0, stream>>>(row_ptr, csr_src, Fh, alpha, b1, Ah, Al);

  // layer 2: 256 -> 4x64, ELU
  pack_w_kernel<<<(256 * 256 + 255) / 256, 256, 0, stream>>>(W2, wth, wtl, 256, 256, 256);
  gemm_attn_kernel<256, 256, 4, 4><<<grid12, 256, 0, stream>>>(Ah, Al, wth, wtl, a2s, a2d,
                                                               Fh, als, ald);
  alpha4_kernel<<<gridN4, 256, 0, stream>>>(row_ptr, csr_src, als, ald, alpha);
  agg_mid_kernel<<<gridN4, 256, 0, stream>>>(row_ptr, csr_src, Fh, alpha, b2, Ah, Al);

  // layer 3: 256 -> 47 (pad 64), no ELU, fp32 out
  pack_w_kernel<<<(64 * 256 + 255) / 256, 256, 0, stream>>>(W3, wth, wtl, 256, 47, 64);
  gemm_attn_kernel<256, 64, 1, 1><<<grid3, 256, 0, stream>>>(Ah, Al, wth, wtl, asv3, adv3,
                                                             Fh, als, ald);
  alpha1_kernel<<<gridN4, 256, 0, stream>>>(row_ptr, csr_src, als, ald, alpha);
  agg_final_kernel<<<gridN4, 256, 0, stream>>>(row_ptr, csr_src, Fh, alpha, b3, out);
}